// Round 3
// baseline (152.482 us; speedup 1.0000x reference)
//
#include <hip/hip_runtime.h>
#include <math.h>

// SSIM loss, fp32, N=16 C=3 H=W=512, 11x11 Gaussian sigma=1.5, zero-padded,
// separable — both blur passes on the MFMA pipe (16x16x32 bf16).
// R11 = R8 skeleton (non-persistent swarm — best measured; persistent R9/R10
// convoyed and regressed) retiled for occupancy + SIMD balance:
//   (a) 4-wave blocks (256 thr), tile 16x48: 4 V-chunks of 16 cols = 64
//       V-cols = 48 out-cols + 10 halo, exactly one V-chunk per wave.
//       R8's 5-wave blocks put 2 waves on one SIMD; every __syncthreads
//       waited on that doubled SIMD (~2x wave-VALU critical path).
//   (b) 8 blocks/CU (32 waves = residency cap, launch_bounds(256,8)) vs
//       R8's 6 blocks/30 waves at 60% measured occupancy: +33% independent
//       memory chains for latency hiding — the binding resource per the
//       counter model (VALU 37%, MFMA 7%, FETCH=compulsory, HBM 24%).
//   (c) grid.x=11 (48-col strips, masked 32-col tail, 3% pad waste).
// Pass V / pass H math and layouts bit-identical to R8. vb stride 68
// (136 B rows -> bank = 2*n16 + ... : <=2-way, free). LDS 12.2 KB.

#define IMG 512
#define TW 48                   // out cols per block (tail block: 32)
#define TH 16
#define GXD 11
#define GYD 32
#define GZD 48
#define NB (GXD * GYD * GZD)    // 16896
#define VBS 68                  // vb row stride in bf16
#define C1c 0.0001f
#define C2c 0.0009f
#define NTOTAL 12582912.0f

typedef short bf16x8 __attribute__((ext_vector_type(8)));
typedef float f32x4 __attribute__((ext_vector_type(4)));
typedef float f32x2 __attribute__((ext_vector_type(2)));

struct GaussB { unsigned short gb[11]; };   // bf16 weights (host-RNE)

// pack bf16(a) low 16, bf16(b) high 16 — one v_perm_b32 (truncation)
__device__ __forceinline__ unsigned int pkbf(float a, float b) {
    return __builtin_amdgcn_perm(__float_as_uint(b), __float_as_uint(a),
                                 0x07060302u);
}

template <bool USE_ATOMIC>
__global__ __launch_bounds__(256, 8) void ssim_main(
    const float* __restrict__ pred,
    const float* __restrict__ target,
    float* __restrict__ sink,
    GaussB gwb)
{
    __shared__ unsigned short Wmat[16][32];       // 1 KB
    __shared__ unsigned short vb[4 + 1][16][VBS]; // 5*16*68*2 = 10880 B
    __shared__ float red[4];

    const int tid  = threadIdx.x;
    const int w    = tid >> 6;        // wave 0..3 = V-chunk id
    const int lane = tid & 63;
    const int quad = lane >> 4;
    const int n16  = lane & 15;
    const int tx0  = blockIdx.x * TW;
    const int ty0  = blockIdx.y * TH;
    const int hw   = (tx0 + TW <= IMG) ? TW : (IMG - tx0);   // 48 or 32
    const float* __restrict__ pbase = pred   + (size_t)blockIdx.z * (IMG * IMG);
    const float* __restrict__ tbase = target + (size_t)blockIdx.z * (IMG * IMG);

    const int gx   = tx0 - 5 + 16 * w + n16;   // this lane's input column
    const bool xin = (unsigned)gx < (unsigned)IMG;
    const int k0   = quad * 8;                 // lane's row offset in 32-window
    const int gy0  = ty0 - 5 + k0;             // first of 8 input rows
    const int vcol = 16 * w + 4 * quad;
    const f32x4 z = {0.0f, 0.0f, 0.0f, 0.0f};

    // ---- loads: 8 vertically-strided pixels of column gx, p and t ----
    float pv[8], tv[8];
    {
        const bool ok = xin & (gy0 >= 0) & (gy0 <= IMG - 8);
        if (ok) {
            const float* pp = pbase + gy0 * IMG + gx;
            const float* tp = tbase + gy0 * IMG + gx;
            #pragma unroll
            for (int j = 0; j < 8; ++j) {
                pv[j] = pp[j * IMG];
                tv[j] = tp[j * IMG];
            }
        } else {
            #pragma unroll
            for (int j = 0; j < 8; ++j) {
                int gy = gy0 + j;
                bool in = xin && ((unsigned)gy < (unsigned)IMG);
                int idx = in ? (gy * IMG + gx) : 0;
                float a = pbase[idx];
                float b = tbase[idx];
                pv[j] = in ? a : 0.0f;
                tv[j] = in ? b : 0.0f;
            }
        }
    }

    // ---- W: W[i][k] = g[k-i] for k-i in [0,10], else 0 ----
    for (int idx = tid; idx < 512; idx += 256) {
        int i = idx >> 5, k = idx & 31, d = k - i;
        Wmat[i][k] = (d >= 0 && d <= 10) ? gwb.gb[d] : 0;
    }
    __syncthreads();
    const bf16x8 wfrag = *(const bf16x8*)&Wmat[n16][quad * 8];

    // ---- Pass V: scale+products in packed fp32, pack bf16, MFMA, vb ----
    const f32x2 halfv = {0.5f, 0.5f};
    f32x2 p2[4], t2[4];
    #pragma unroll
    for (int h = 0; h < 4; ++h) {
        f32x2 pr = {pv[2*h], pv[2*h+1]};
        f32x2 tr = {tv[2*h], tv[2*h+1]};
        p2[h] = pr * halfv + halfv;     // v_pk_fma_f32
        t2[h] = tr * halfv + halfv;
    }
    #pragma unroll
    for (int ch = 0; ch < 5; ++ch) {
        union { bf16x8 v; unsigned int u[4]; } f;
        #pragma unroll
        for (int h = 0; h < 4; ++h) {
            f32x2 q;
            if      (ch == 0) q = p2[h];
            else if (ch == 1) q = t2[h];
            else if (ch == 2) q = p2[h] * p2[h];   // v_pk_mul_f32
            else if (ch == 3) q = t2[h] * t2[h];
            else              q = p2[h] * t2[h];
            f.u[h] = pkbf(q.x, q.y);
        }
        f32x4 d = __builtin_amdgcn_mfma_f32_16x16x32_bf16(f.v, wfrag, z, 0, 0, 0);
        union { ushort4 s; unsigned int u[2]; } pk;
        pk.u[0] = pkbf(d[0], d[1]);
        pk.u[1] = pkbf(d[2], d[3]);
        *(ushort4*)&vb[ch][n16][vcol] = pk.s;
    }
    __syncthreads();

    // ---- Pass H: wave w -> output cols tx0+16w .. +15 (if within strip) ----
    float lsum = 0.0f;
    if (16 * w < hw) {
        f32x4 r[5];
        #pragma unroll
        for (int ch = 0; ch < 5; ++ch) {
            bf16x8 a = *(const bf16x8*)&vb[ch][n16][16 * w + 8 * quad];
            r[ch] = __builtin_amdgcn_mfma_f32_16x16x32_bf16(a, wfrag, z, 0, 0, 0);
        }
        const f32x2 twov = {2.0f, 2.0f};
        const f32x2 c1v  = {C1c, C1c};
        const f32x2 c2v  = {C2c, C2c};
        #pragma unroll
        for (int jj = 0; jj < 2; ++jj) {
            f32x2 mp  = {r[0][2*jj], r[0][2*jj+1]};
            f32x2 mt  = {r[1][2*jj], r[1][2*jj+1]};
            f32x2 epp = {r[2][2*jj], r[2][2*jj+1]};
            f32x2 ett = {r[3][2*jj], r[3][2*jj+1]};
            f32x2 ept = {r[4][2*jj], r[4][2*jj+1]};
            f32x2 mp2 = mp * mp;
            f32x2 mt2 = mt * mt;
            f32x2 mpt = mp * mt;
            f32x2 sp_ = epp - mp2;
            f32x2 st_ = ett - mt2;
            f32x2 spt = ept - mpt;
            f32x2 num = (mpt * twov + c1v) * (spt * twov + c2v);
            f32x2 den = (mp2 + mt2 + c1v) * (sp_ + st_ + c2v);
            lsum = fmaf(num.x, __builtin_amdgcn_rcpf(den.x), lsum);
            lsum = fmaf(num.y, __builtin_amdgcn_rcpf(den.y), lsum);
        }
    }

    // ---- block reduction ----
    #pragma unroll
    for (int off = 32; off > 0; off >>= 1)
        lsum += __shfl_down(lsum, off, 64);
    if (lane == 0) red[w] = lsum;
    __syncthreads();
    if (tid == 0) {
        float s = red[0] + red[1] + red[2] + red[3];
        if (USE_ATOMIC) {
            atomicAdd(sink, s);
        } else {
            int bid = blockIdx.x + GXD * (blockIdx.y + GYD * blockIdx.z);
            sink[bid] = s;
        }
    }
}

__global__ __launch_bounds__(256) void ssim_reduce(const float* __restrict__ partials,
                                                   float* __restrict__ out)
{
    __shared__ float red[4];
    const int tid = threadIdx.x;
    float s = 0.0f;
    const float4* p4 = (const float4*)partials;
    for (int j = tid; j < NB / 4; j += 256) {   // 16896/4 = 4224 float4
        float4 v = p4[j];
        s += v.x + v.y + v.z + v.w;
    }
    #pragma unroll
    for (int off = 32; off > 0; off >>= 1)
        s += __shfl_down(s, off, 64);
    if ((tid & 63) == 0) red[tid >> 6] = s;
    __syncthreads();
    if (tid == 0)
        out[0] = 1.0f - (red[0] + red[1] + red[2] + red[3]) / NTOTAL;
}

__global__ void ssim_zero(float* accum) { accum[0] = 0.0f; }
__global__ void ssim_final(const float* accum, float* out) {
    out[0] = 1.0f - accum[0] / NTOTAL;
}

extern "C" void kernel_launch(void* const* d_in, const int* in_sizes, int n_in,
                              void* d_out, int out_size, void* d_ws, size_t ws_size,
                              hipStream_t stream) {
    const float* pred   = (const float*)d_in[0];
    const float* target = (const float*)d_in[1];
    float* out = (float*)d_out;

    // Gaussian weights in double, RNE-rounded to bf16 on host
    GaussB gwb;
    double vals[11], s = 0.0;
    for (int i = 0; i < 11; ++i) {
        double d = (double)i - 5.0;
        vals[i] = exp(-(d * d) / (2.0 * 1.5 * 1.5));
        s += vals[i];
    }
    for (int i = 0; i < 11; ++i) {
        float f = (float)(vals[i] / s);
        unsigned int u;
        __builtin_memcpy(&u, &f, 4);
        unsigned int rounded = (u + 0x7FFFu + ((u >> 16) & 1u)) >> 16;  // RNE
        gwb.gb[i] = (unsigned short)rounded;
    }

    dim3 grid(GXD, GYD, GZD);   // 11 x 32 x 48 = 16896 blocks
    if (ws_size >= (size_t)NB * sizeof(float)) {
        float* partials = (float*)d_ws;
        ssim_main<false><<<grid, 256, 0, stream>>>(pred, target, partials, gwb);
        ssim_reduce<<<1, 256, 0, stream>>>(partials, out);
    } else {
        float* accum = (float*)d_ws;
        ssim_zero<<<1, 1, 0, stream>>>(accum);
        ssim_main<true><<<grid, 256, 0, stream>>>(pred, target, accum, gwb);
        ssim_final<<<1, 1, 0, stream>>>(accum, out);
    }
}

// Round 4
// 137.588 us; speedup vs baseline: 1.1083x; 1.1083x over previous
//
#include <hip/hip_runtime.h>
#include <math.h>

// SSIM loss, fp32, N=16 C=3 H=W=512, 11x11 Gaussian sigma=1.5, zero-padded,
// separable — both blur passes on the MFMA pipe (16x16x32 bf16).
// R12 = exact R8 skeleton (best measured: 49.3 µs; non-persistent swarm,
// GXD=8 == XCD count so y-neighbor tiles share an XCD-L2 and the vertical
// halo stays cached — R11 proved breaking this doubles HBM fetch) with the
// per-block fixed overhead (~400 cyc of 2465) surgically removed:
//   (a) Wmat built ONCE on host, copied to d_ws via hipMemcpyAsync;
//       wfrag = one L2-hot global_load_dwordx4. Kills the per-block build
//       loop, the LDS array, and barrier #1.
//   (b) per-wave partial stores partials[bid*4+w]: kills red[], barrier #3,
//       and the tid0 serial tail that delayed block-slot recycling.
//   (c) ssim_reduce at 1024 threads for the 4x partial array.
// Pass V / pass H math, layouts, grid bit-identical to R8. Atomic fallback
// (ws too small) is verbatim R8. LDS 14.1 KB; launch_bounds(320,6).

#define IMG 512
#define TW 64
#define TH 16
#define GXD 8
#define GYD 32
#define GZD 48
#define NB (GXD * GYD * GZD)    // 12288
#define NB4 (NB * 4)            // per-wave partials
#define VBS 88                  // vb row stride in bf16 (16B-aligned)
#define C1c 0.0001f
#define C2c 0.0009f
#define NTOTAL 12582912.0f
#define WS_NEED (1024 + (size_t)NB4 * 4)

typedef short bf16x8 __attribute__((ext_vector_type(8)));
typedef float f32x4 __attribute__((ext_vector_type(4)));
typedef float f32x2 __attribute__((ext_vector_type(2)));

struct GaussB { unsigned short gb[11]; };   // bf16 weights (host-RNE)

// pack bf16(a) low 16, bf16(b) high 16 — one v_perm_b32 (truncation)
__device__ __forceinline__ unsigned int pkbf(float a, float b) {
    return __builtin_amdgcn_perm(__float_as_uint(b), __float_as_uint(a),
                                 0x07060302u);
}

// ---------------- shared device pieces (identical math to R8) -------------

__device__ __forceinline__ void load_px(const float* __restrict__ pbase,
                                        const float* __restrict__ tbase,
                                        int gx, bool xin, int gy0,
                                        float (&pv)[8], float (&tv)[8]) {
    const bool ok = xin & (gy0 >= 0) & (gy0 <= IMG - 8);
    if (ok) {
        const float* pp = pbase + gy0 * IMG + gx;
        const float* tp = tbase + gy0 * IMG + gx;
        #pragma unroll
        for (int j = 0; j < 8; ++j) {
            pv[j] = pp[j * IMG];
            tv[j] = tp[j * IMG];
        }
    } else {
        #pragma unroll
        for (int j = 0; j < 8; ++j) {
            int gy = gy0 + j;
            bool in = xin && ((unsigned)gy < (unsigned)IMG);
            int idx = in ? (gy * IMG + gx) : 0;
            float a = pbase[idx];
            float b = tbase[idx];
            pv[j] = in ? a : 0.0f;
            tv[j] = in ? b : 0.0f;
        }
    }
}

__device__ __forceinline__ void pass_v_body(
    const float (&pv)[8], const float (&tv)[8], bf16x8 wfrag,
    unsigned short (*vb)[16][VBS], int n16, int vcol) {
    const f32x4 z = {0.0f, 0.0f, 0.0f, 0.0f};
    const f32x2 halfv = {0.5f, 0.5f};
    f32x2 p2[4], t2[4];
    #pragma unroll
    for (int h = 0; h < 4; ++h) {
        f32x2 pr = {pv[2*h], pv[2*h+1]};
        f32x2 tr = {tv[2*h], tv[2*h+1]};
        p2[h] = pr * halfv + halfv;     // v_pk_fma_f32
        t2[h] = tr * halfv + halfv;
    }
    #pragma unroll
    for (int ch = 0; ch < 5; ++ch) {
        union { bf16x8 v; unsigned int u[4]; } f;
        #pragma unroll
        for (int h = 0; h < 4; ++h) {
            f32x2 q;
            if      (ch == 0) q = p2[h];
            else if (ch == 1) q = t2[h];
            else if (ch == 2) q = p2[h] * p2[h];   // v_pk_mul_f32
            else if (ch == 3) q = t2[h] * t2[h];
            else              q = p2[h] * t2[h];
            f.u[h] = pkbf(q.x, q.y);
        }
        f32x4 d = __builtin_amdgcn_mfma_f32_16x16x32_bf16(f.v, wfrag, z, 0, 0, 0);
        union { ushort4 s; unsigned int u[2]; } pk;
        pk.u[0] = pkbf(d[0], d[1]);
        pk.u[1] = pkbf(d[2], d[3]);
        *(ushort4*)&vb[ch][n16][vcol] = pk.s;
    }
}

__device__ __forceinline__ float pass_h_body(
    unsigned short (*vb)[16][VBS], bf16x8 wfrag, int n16, int quad, int w) {
    const f32x4 z = {0.0f, 0.0f, 0.0f, 0.0f};
    float lsum = 0.0f;
    f32x4 r[5];
    #pragma unroll
    for (int ch = 0; ch < 5; ++ch) {
        bf16x8 a = *(const bf16x8*)&vb[ch][n16][16 * w + 8 * quad];
        r[ch] = __builtin_amdgcn_mfma_f32_16x16x32_bf16(a, wfrag, z, 0, 0, 0);
    }
    const f32x2 twov = {2.0f, 2.0f};
    const f32x2 c1v  = {C1c, C1c};
    const f32x2 c2v  = {C2c, C2c};
    #pragma unroll
    for (int jj = 0; jj < 2; ++jj) {
        f32x2 mp  = {r[0][2*jj], r[0][2*jj+1]};
        f32x2 mt  = {r[1][2*jj], r[1][2*jj+1]};
        f32x2 epp = {r[2][2*jj], r[2][2*jj+1]};
        f32x2 ett = {r[3][2*jj], r[3][2*jj+1]};
        f32x2 ept = {r[4][2*jj], r[4][2*jj+1]};
        f32x2 mp2 = mp * mp;
        f32x2 mt2 = mt * mt;
        f32x2 mpt = mp * mt;
        f32x2 sp_ = epp - mp2;
        f32x2 st_ = ett - mt2;
        f32x2 spt = ept - mpt;
        f32x2 num = (mpt * twov + c1v) * (spt * twov + c2v);
        f32x2 den = (mp2 + mt2 + c1v) * (sp_ + st_ + c2v);
        lsum = fmaf(num.x, __builtin_amdgcn_rcpf(den.x), lsum);
        lsum = fmaf(num.y, __builtin_amdgcn_rcpf(den.y), lsum);
    }
    return lsum;
}

// ---------------- main kernel, workspace path (R12) -----------------------

__global__ __launch_bounds__(320, 6) void ssim_main_ws(
    const float* __restrict__ pred,
    const float* __restrict__ target,
    const unsigned short* __restrict__ wtab,   // 16x32 bf16 W matrix in ws
    float* __restrict__ partials)              // NB4 per-wave partials
{
    __shared__ unsigned short vb[5][16][VBS];     // 14080 B

    const int tid  = threadIdx.x;
    const int w    = tid >> 6;        // wave 0..4 = V-chunk id
    const int lane = tid & 63;
    const int quad = lane >> 4;
    const int n16  = lane & 15;
    const int tx0  = blockIdx.x * TW;
    const int ty0  = blockIdx.y * TH;
    const float* __restrict__ pbase = pred   + (size_t)blockIdx.z * (IMG * IMG);
    const float* __restrict__ tbase = target + (size_t)blockIdx.z * (IMG * IMG);

    const int gx   = tx0 - 5 + 16 * w + n16;   // this lane's input column
    const bool xin = (unsigned)gx < (unsigned)IMG;
    const int gy0  = ty0 - 5 + quad * 8;       // first of 8 input rows
    const int vcol = 16 * w + 4 * quad;

    // wfrag: one L2-hot 16B load, overlaps the pixel loads
    const bf16x8 wfrag = *(const bf16x8*)(wtab + n16 * 32 + quad * 8);

    float pv[8], tv[8];
    load_px(pbase, tbase, gx, xin, gy0, pv, tv);

    pass_v_body(pv, tv, wfrag, vb, n16, vcol);
    __syncthreads();                 // the single remaining barrier

    float lsum = 0.0f;
    if (w < 4)
        lsum = pass_h_body(vb, wfrag, n16, quad, w);

    #pragma unroll
    for (int off = 32; off > 0; off >>= 1)
        lsum += __shfl_down(lsum, off, 64);
    if (lane == 0 && w < 4) {
        int bid = blockIdx.x + GXD * (blockIdx.y + GYD * blockIdx.z);
        partials[bid * 4 + w] = lsum;
    }
}

// ---------------- atomic fallback = verbatim R8 ---------------------------

__global__ __launch_bounds__(320, 6) void ssim_main_atomic(
    const float* __restrict__ pred,
    const float* __restrict__ target,
    float* __restrict__ sink,
    GaussB gwb)
{
    __shared__ unsigned short Wmat[16][32];
    __shared__ unsigned short vb[5][16][VBS];
    __shared__ float red[5];

    const int tid  = threadIdx.x;
    const int w    = tid >> 6;
    const int lane = tid & 63;
    const int quad = lane >> 4;
    const int n16  = lane & 15;
    const int tx0  = blockIdx.x * TW;
    const int ty0  = blockIdx.y * TH;
    const float* __restrict__ pbase = pred   + (size_t)blockIdx.z * (IMG * IMG);
    const float* __restrict__ tbase = target + (size_t)blockIdx.z * (IMG * IMG);

    const int gx   = tx0 - 5 + 16 * w + n16;
    const bool xin = (unsigned)gx < (unsigned)IMG;
    const int gy0  = ty0 - 5 + quad * 8;
    const int vcol = 16 * w + 4 * quad;

    float pv[8], tv[8];
    load_px(pbase, tbase, gx, xin, gy0, pv, tv);

    for (int idx = tid; idx < 512; idx += 320) {
        int i = idx >> 5, k = idx & 31, d = k - i;
        Wmat[i][k] = (d >= 0 && d <= 10) ? gwb.gb[d] : 0;
    }
    __syncthreads();
    const bf16x8 wfrag = *(const bf16x8*)&Wmat[n16][quad * 8];

    pass_v_body(pv, tv, wfrag, vb, n16, vcol);
    __syncthreads();

    float lsum = 0.0f;
    if (w < 4)
        lsum = pass_h_body(vb, wfrag, n16, quad, w);

    #pragma unroll
    for (int off = 32; off > 0; off >>= 1)
        lsum += __shfl_down(lsum, off, 64);
    if (lane == 0) red[w] = lsum;
    __syncthreads();
    if (tid == 0)
        atomicAdd(sink, red[0] + red[1] + red[2] + red[3]);
}

// ---------------- reductions ----------------------------------------------

__global__ __launch_bounds__(1024) void ssim_reduce(const float* __restrict__ partials,
                                                    float* __restrict__ out)
{
    __shared__ float red[16];
    const int tid = threadIdx.x;
    float s = 0.0f;
    const float4* p4 = (const float4*)partials;
    #pragma unroll
    for (int j = 0; j < NB4 / 4096; ++j) {   // 49152/4 = 12288 f4 / 1024
        float4 v = p4[tid + 1024 * j];
        s += v.x + v.y + v.z + v.w;
    }
    #pragma unroll
    for (int off = 32; off > 0; off >>= 1)
        s += __shfl_down(s, off, 64);
    if ((tid & 63) == 0) red[tid >> 6] = s;
    __syncthreads();
    if (tid == 0) {
        float t = 0.0f;
        #pragma unroll
        for (int k = 0; k < 16; ++k) t += red[k];
        out[0] = 1.0f - t / NTOTAL;
    }
}

__global__ void ssim_zero(float* accum) { accum[0] = 0.0f; }
__global__ void ssim_final(const float* accum, float* out) {
    out[0] = 1.0f - accum[0] / NTOTAL;
}

// ---------------- host ----------------------------------------------------

static unsigned short g_hostW[512];   // static: must outlive async copy

extern "C" void kernel_launch(void* const* d_in, const int* in_sizes, int n_in,
                              void* d_out, int out_size, void* d_ws, size_t ws_size,
                              hipStream_t stream) {
    const float* pred   = (const float*)d_in[0];
    const float* target = (const float*)d_in[1];
    float* out = (float*)d_out;

    // Gaussian weights in double, RNE-rounded to bf16 on host
    GaussB gwb;
    double vals[11], s = 0.0;
    for (int i = 0; i < 11; ++i) {
        double d = (double)i - 5.0;
        vals[i] = exp(-(d * d) / (2.0 * 1.5 * 1.5));
        s += vals[i];
    }
    for (int i = 0; i < 11; ++i) {
        float f = (float)(vals[i] / s);
        unsigned int u;
        __builtin_memcpy(&u, &f, 4);
        unsigned int rounded = (u + 0x7FFFu + ((u >> 16) & 1u)) >> 16;  // RNE
        gwb.gb[i] = (unsigned short)rounded;
    }
    // full 16x32 W matrix: W[i][k] = g[k-i] for k-i in [0,10], else 0
    for (int i = 0; i < 16; ++i)
        for (int k = 0; k < 32; ++k) {
            int d = k - i;
            g_hostW[i * 32 + k] = (d >= 0 && d <= 10) ? gwb.gb[d] : 0;
        }

    dim3 grid(GXD, GYD, GZD);   // 8 x 32 x 48 = 12288 blocks
    if (ws_size >= WS_NEED) {
        unsigned short* wtab = (unsigned short*)d_ws;            // 1 KB
        float* partials = (float*)((char*)d_ws + 1024);          // NB4 floats
        hipMemcpyAsync(wtab, g_hostW, sizeof(g_hostW),
                       hipMemcpyHostToDevice, stream);
        ssim_main_ws<<<grid, 320, 0, stream>>>(pred, target, wtab, partials);
        ssim_reduce<<<1, 1024, 0, stream>>>(partials, out);
    } else {
        float* accum = (float*)d_ws;
        ssim_zero<<<1, 1, 0, stream>>>(accum);
        ssim_main_atomic<<<grid, 320, 0, stream>>>(pred, target, accum, gwb);
        ssim_final<<<1, 1, 0, stream>>>(accum, out);
    }
}